// Round 1
// baseline (1941.859 us; speedup 1.0000x reference)
//
#include <hip/hip_runtime.h>
#include <cstdint>
#include <cstddef>

// ---------------------------------------------------------------------------
// Llama decoder layer, MI355X. B=2 S=1024 H=4096 NQ=32 NKV=8 D=128 I=11008.
// All GEMMs: bf16 MFMA 16x16x32, m97 structure (128x128 tile, BK=32,
// global_load_lds width 16). Weights transposed+converted to bf16 [N][K]
// once per call so every GEMM is "TN" with K-contiguous operands.
// ---------------------------------------------------------------------------

typedef __bf16 bf16;
typedef __attribute__((ext_vector_type(8))) __bf16 bf16x8;
typedef __attribute__((ext_vector_type(4))) float f32x4;

#define GLDS16(gptr, lptr)                                                    \
  __builtin_amdgcn_global_load_lds(                                           \
      (const __attribute__((address_space(1))) void*)(gptr),                  \
      (__attribute__((address_space(3))) void*)(lptr), 16, 0, 0)

#define S_LEN 1024
#define H_DIM 4096
#define NQ_H 32
#define NKV_H 8
#define HD 128
#define I_DIM 11008

// ---------------------------------------------------------------------------
// Weight transpose + fp32->bf16: src [K][N] f32 -> dst [N][K] bf16
// ---------------------------------------------------------------------------
__global__ __launch_bounds__(256) void wtrans_kernel(
    const float* __restrict__ src, bf16* __restrict__ dst, int K, int N) {
  const int tx = threadIdx.x & 31, ty = threadIdx.x >> 5;
  const int n0 = blockIdx.x * 32, k0 = blockIdx.y * 32;
  __shared__ float t[32][33];
#pragma unroll
  for (int j = 0; j < 4; j++)
    t[ty + j * 8][tx] = src[(size_t)(k0 + ty + j * 8) * N + n0 + tx];
  __syncthreads();
#pragma unroll
  for (int j = 0; j < 4; j++)
    dst[(size_t)(n0 + ty + j * 8) * K + k0 + tx] = (bf16)t[tx][ty + j * 8];
}

// ---------------------------------------------------------------------------
// RMSNorm: x f32 [rows][4096] -> out bf16, one block per row
// ---------------------------------------------------------------------------
__global__ __launch_bounds__(256) void rmsnorm_kernel(
    const float* __restrict__ x, const float* __restrict__ w,
    bf16* __restrict__ out) {
  const int row = blockIdx.x;
  const float4* xr = (const float4*)(x + (size_t)row * H_DIM);
  float4 v[4];
  float s = 0.f;
#pragma unroll
  for (int i = 0; i < 4; i++) {
    v[i] = xr[threadIdx.x + i * 256];
    s += v[i].x * v[i].x + v[i].y * v[i].y + v[i].z * v[i].z + v[i].w * v[i].w;
  }
#pragma unroll
  for (int m = 1; m < 64; m <<= 1) s += __shfl_xor(s, m);
  __shared__ float red[4];
  if ((threadIdx.x & 63) == 0) red[threadIdx.x >> 6] = s;
  __syncthreads();
  s = red[0] + red[1] + red[2] + red[3];
  const float r = rsqrtf(s * (1.f / H_DIM) + 1e-5f);
  bf16* o = out + (size_t)row * H_DIM;
  const float4* wr = (const float4*)w;
#pragma unroll
  for (int i = 0; i < 4; i++) {
    float4 wv = wr[threadIdx.x + i * 256];
    int idx = (threadIdx.x + i * 256) * 4;
    o[idx + 0] = (bf16)(v[i].x * r * wv.x);
    o[idx + 1] = (bf16)(v[i].y * r * wv.y);
    o[idx + 2] = (bf16)(v[i].z * r * wv.z);
    o[idx + 3] = (bf16)(v[i].w * r * wv.w);
  }
}

// ---------------------------------------------------------------------------
// GEMM TN: C[M][N] = A[M][K](bf16) * Bt[N][K](bf16)^T.
// MODE 0: bf16 out. MODE 1: f32 out. MODE 2: f32 out + resid add.
// ---------------------------------------------------------------------------
template <int MODE>
__global__ __launch_bounds__(256) void gemm_tn(
    const bf16* __restrict__ A, const bf16* __restrict__ Bt,
    void* __restrict__ Cout, const float* __restrict__ resid,
    int M, int N, int K) {
  __shared__ __align__(16) bf16 As[128 * 32];
  __shared__ __align__(16) bf16 Bs[128 * 32];
  const int tid = threadIdx.x;
  const int wave = tid >> 6, lane = tid & 63;
  const int lr = lane & 15, quad = lane >> 4;
  const int m0 = blockIdx.y * 128, n0 = blockIdx.x * 128;
  const int wm = (wave & 1) * 64, wn = (wave >> 1) * 64;

  // staging: 8 chunks of 1KB each for A and B; wave w owns chunks 2w, 2w+1.
  const int c0 = wave * 2;
  const int ar0 = (c0 * 64 + lane) >> 2;        // tile row, chunk c0
  const int ar1 = (c0 * 64 + 64 + lane) >> 2;   // tile row, chunk c0+1
  const int acol = (lane & 3) * 8;
  const bf16* Ag0 = A + (size_t)(m0 + ar0) * K + acol;
  const bf16* Ag1 = A + (size_t)(m0 + ar1) * K + acol;
  const bf16* Bg0 = Bt + (size_t)(n0 + ar0) * K + acol;
  const bf16* Bg1 = Bt + (size_t)(n0 + ar1) * K + acol;
  bf16* As0 = As + c0 * 512;
  bf16* Bs0 = Bs + c0 * 512;

  f32x4 acc[4][4] = {};

  for (int k0 = 0; k0 < K; k0 += 32) {
    __syncthreads();
    GLDS16(Ag0 + k0, As0);
    GLDS16(Ag1 + k0, As0 + 512);
    GLDS16(Bg0 + k0, Bs0);
    GLDS16(Bg1 + k0, Bs0 + 512);
    __syncthreads();
    bf16x8 af[4], bfr[4];
#pragma unroll
    for (int i = 0; i < 4; i++)
      af[i] = *(const bf16x8*)&As[(wm + i * 16 + lr) * 32 + quad * 8];
#pragma unroll
    for (int j = 0; j < 4; j++)
      bfr[j] = *(const bf16x8*)&Bs[(wn + j * 16 + lr) * 32 + quad * 8];
#pragma unroll
    for (int i = 0; i < 4; i++)
#pragma unroll
      for (int j = 0; j < 4; j++)
        acc[i][j] = __builtin_amdgcn_mfma_f32_16x16x32_bf16(af[i], bfr[j],
                                                            acc[i][j], 0, 0, 0);
  }

#pragma unroll
  for (int i = 0; i < 4; i++)
#pragma unroll
    for (int j = 0; j < 4; j++)
#pragma unroll
      for (int r = 0; r < 4; r++) {
        const size_t row = m0 + wm + i * 16 + quad * 4 + r;
        const size_t col = n0 + wn + j * 16 + lr;
        const float v = acc[i][j][r];
        if (MODE == 0)
          ((bf16*)Cout)[row * N + col] = (bf16)v;
        else if (MODE == 1)
          ((float*)Cout)[row * N + col] = v;
        else
          ((float*)Cout)[row * N + col] = v + resid[row * N + col];
      }
}

// ---------------------------------------------------------------------------
// RoPE: qkv f32 [2048][6144] -> qb bf16 [2048][4096] (scaled by 1/sqrt(D)),
//       kb bf16 [2048][1024]
// ---------------------------------------------------------------------------
__global__ __launch_bounds__(256) void rope_kernel(
    const float* __restrict__ qkv, const float* __restrict__ cosT,
    const float* __restrict__ sinT, bf16* __restrict__ qb,
    bf16* __restrict__ kb) {
  const int row = blockIdx.x;
  const int s = row & (S_LEN - 1);
  const float* base = qkv + (size_t)row * 6144;
  const float scale = 0.08838834764831845f;  // 1/sqrt(128)
  for (int p = threadIdx.x; p < 2560; p += 256) {
    const int hd = p >> 6;
    const int d = p & 63;
    const float c = cosT[s * HD + d], sn = sinT[s * HD + d];
    if (hd < NQ_H) {
      const float* qp = base + hd * HD;
      const float x1 = qp[d], x2 = qp[d + 64];
      bf16* o = qb + (size_t)row * H_DIM + hd * HD;
      o[d] = (bf16)((x1 * c - x2 * sn) * scale);
      o[d + 64] = (bf16)((x2 * c + x1 * sn) * scale);
    } else {
      const int kh = hd - NQ_H;
      const float* kp = base + H_DIM + kh * HD;
      const float x1 = kp[d], x2 = kp[d + 64];
      bf16* o = kb + (size_t)row * (NKV_H * HD) + kh * HD;
      o[d] = (bf16)(x1 * c - x2 * sn);
      o[d + 64] = (bf16)(x2 * c + x1 * sn);
    }
  }
}

// ---------------------------------------------------------------------------
// V transpose: qkv f32 (v part at col 5120) -> vt bf16 [B][KV][128][S]
// ---------------------------------------------------------------------------
__global__ __launch_bounds__(256) void vtrans_kernel(
    const float* __restrict__ qkv, bf16* __restrict__ vt) {
  const int tx = threadIdx.x & 31, ty = threadIdx.x >> 5;
  const int s0 = blockIdx.x * 32, d0 = blockIdx.y * 32;
  const int b = blockIdx.z >> 3, kv = blockIdx.z & 7;
  __shared__ float t[32][33];
#pragma unroll
  for (int j = 0; j < 4; j++) {
    const int s = s0 + ty + j * 8;
    t[ty + j * 8][tx] =
        qkv[(size_t)(b * S_LEN + s) * 6144 + 5120 + kv * HD + d0 + tx];
  }
  __syncthreads();
#pragma unroll
  for (int j = 0; j < 4; j++) {
    const int d = d0 + ty + j * 8;
    vt[((size_t)(b * NKV_H + kv) * HD + d) * S_LEN + s0 + tx] =
        (bf16)t[tx][ty + j * 8];
  }
}

// ---------------------------------------------------------------------------
// Flash attention. Grid (S/128, NQ, B), 256 threads (4 waves, 32 q-rows each).
// Q pre-scaled by 1/sqrt(D). K-tiles of 64 keys. LDS tiles stored as
// [kstep][rows][32] slices so all ds_reads use the 64B-stride b128 pattern.
// ---------------------------------------------------------------------------
__global__ __launch_bounds__(256) void attn_fwd(
    const bf16* __restrict__ Qb, const bf16* __restrict__ Kb,
    const bf16* __restrict__ Vtb, bf16* __restrict__ Ob) {
  __shared__ __align__(16) bf16 Ks[16 * 512];  // [4 ks][64 key][32 d]
  __shared__ __align__(16) bf16 Vs[16 * 512];  // [2 ks][128 d][32 key]
  __shared__ __align__(16) bf16 Ps[16 * 512];  // [2 ks][128 q][32 key]
  const int tid = threadIdx.x;
  const int wave = tid >> 6, lane = tid & 63;
  const int lr = lane & 15, quad = lane >> 4;
  const int qt = blockIdx.x, h = blockIdx.y, b = blockIdx.z;
  const int kv = h >> 2;
  const int qrow0 = qt * 128 + wave * 32;

  bf16x8 qf[2][4];
#pragma unroll
  for (int mi = 0; mi < 2; mi++)
#pragma unroll
    for (int ks = 0; ks < 4; ks++)
      qf[mi][ks] = *(const bf16x8*)&Qb[(size_t)(b * S_LEN + qrow0 + mi * 16 + lr) *
                                           H_DIM +
                                       h * HD + ks * 32 + quad * 8];

  f32x4 oacc[2][8] = {};
  float m_i[2][4], l_i[2][4];
#pragma unroll
  for (int mi = 0; mi < 2; mi++)
#pragma unroll
    for (int r = 0; r < 4; r++) {
      m_i[mi][r] = -__builtin_inff();
      l_i[mi][r] = 0.f;
    }

  const int nk = 2 * (qt + 1);
  const int maxrow = qrow0 + 31;
  const int srow = lane >> 2;
  const int scol = (lane & 3) * 8;

  for (int kt = 0; kt < nk; kt++) {
    const int k0 = kt * 64;
    __syncthreads();
#pragma unroll
    for (int i = 0; i < 4; i++) {
      const int c = wave * 4 + i;
      {
        const int ks = c >> 2, sc = c & 3;
        const int key = sc * 16 + srow;
        GLDS16(Kb + (size_t)(b * S_LEN + k0 + key) * (NKV_H * HD) + kv * HD +
                   ks * 32 + scol,
               Ks + c * 512);
      }
      {
        const int ks2 = c >> 3, sc2 = c & 7;
        const int d = sc2 * 16 + srow;
        GLDS16(Vtb + ((size_t)(b * NKV_H + kv) * HD + d) * S_LEN + k0 +
                   ks2 * 32 + scol,
               Vs + c * 512);
      }
    }
    __syncthreads();
    const bool active = (k0 <= maxrow);
    float alpha[2][4];
    if (active) {
      f32x4 sacc[2][4];
#pragma unroll
      for (int mi = 0; mi < 2; mi++)
#pragma unroll
        for (int nj = 0; nj < 4; nj++) sacc[mi][nj] = (f32x4){0.f, 0.f, 0.f, 0.f};
#pragma unroll
      for (int ks = 0; ks < 4; ks++) {
        bf16x8 kf[4];
#pragma unroll
        for (int nj = 0; nj < 4; nj++)
          kf[nj] = *(const bf16x8*)&Ks[ks * 2048 + (nj * 16 + lr) * 32 + quad * 8];
#pragma unroll
        for (int mi = 0; mi < 2; mi++)
#pragma unroll
          for (int nj = 0; nj < 4; nj++)
            sacc[mi][nj] = __builtin_amdgcn_mfma_f32_16x16x32_bf16(
                qf[mi][ks], kf[nj], sacc[mi][nj], 0, 0, 0);
      }
      // causal mask + online softmax
#pragma unroll
      for (int mi = 0; mi < 2; mi++) {
#pragma unroll
        for (int r = 0; r < 4; r++) {
          const int row = qrow0 + mi * 16 + quad * 4 + r;
          float best = -__builtin_inff();
#pragma unroll
          for (int nj = 0; nj < 4; nj++) {
            const int col = k0 + nj * 16 + lr;
            if (col > row) sacc[mi][nj][r] = -__builtin_inff();
            best = fmaxf(best, sacc[mi][nj][r]);
          }
#pragma unroll
          for (int m = 1; m < 16; m <<= 1)
            best = fmaxf(best, __shfl_xor(best, m));
          const float mnew = fmaxf(m_i[mi][r], best);
          alpha[mi][r] = __expf(m_i[mi][r] - mnew);
          m_i[mi][r] = mnew;
          float ssum = 0.f;
#pragma unroll
          for (int nj = 0; nj < 4; nj++) {
            const float p = __expf(sacc[mi][nj][r] - mnew);
            sacc[mi][nj][r] = p;
            ssum += p;
          }
#pragma unroll
          for (int m = 1; m < 16; m <<= 1) ssum += __shfl_xor(ssum, m);
          l_i[mi][r] = l_i[mi][r] * alpha[mi][r] + ssum;
        }
      }
      // rescale O
#pragma unroll
      for (int mi = 0; mi < 2; mi++)
#pragma unroll
        for (int dj = 0; dj < 8; dj++)
#pragma unroll
          for (int r = 0; r < 4; r++) oacc[mi][dj][r] *= alpha[mi][r];
      // write P (own rows only)
#pragma unroll
      for (int mi = 0; mi < 2; mi++)
#pragma unroll
        for (int nj = 0; nj < 4; nj++) {
          const int ks2 = nj >> 1;
          const int k32 = (nj & 1) * 16 + lr;
#pragma unroll
          for (int r = 0; r < 4; r++) {
            const int rowl = wave * 32 + mi * 16 + quad * 4 + r;
            Ps[ks2 * 4096 + rowl * 32 + k32] = (bf16)sacc[mi][nj][r];
          }
        }
    }
    __syncthreads();
    if (active) {
#pragma unroll
      for (int ks2 = 0; ks2 < 2; ks2++) {
        bf16x8 pf[2], vf[8];
#pragma unroll
        for (int mi = 0; mi < 2; mi++)
          pf[mi] = *(const bf16x8*)&Ps[ks2 * 4096 +
                                       (wave * 32 + mi * 16 + lr) * 32 + quad * 8];
#pragma unroll
        for (int dj = 0; dj < 8; dj++)
          vf[dj] = *(const bf16x8*)&Vs[ks2 * 4096 + (dj * 16 + lr) * 32 + quad * 8];
#pragma unroll
        for (int mi = 0; mi < 2; mi++)
#pragma unroll
          for (int dj = 0; dj < 8; dj++)
            oacc[mi][dj] = __builtin_amdgcn_mfma_f32_16x16x32_bf16(
                pf[mi], vf[dj], oacc[mi][dj], 0, 0, 0);
      }
    }
  }
  // epilogue: O / l
#pragma unroll
  for (int mi = 0; mi < 2; mi++)
#pragma unroll
    for (int r = 0; r < 4; r++) {
      const float rinv = 1.f / l_i[mi][r];
      const size_t row = (size_t)b * S_LEN + qrow0 + mi * 16 + quad * 4 + r;
#pragma unroll
      for (int dj = 0; dj < 8; dj++)
        Ob[row * H_DIM + h * HD + dj * 16 + lr] =
            (bf16)(oacc[mi][dj][r] * rinv);
    }
}

// ---------------------------------------------------------------------------
// SwiGLU: act = silu(gate) * up, bf16, vectorized x8. In-place safe.
// ---------------------------------------------------------------------------
__global__ __launch_bounds__(256) void swiglu_kernel(
    const bf16* __restrict__ gate, const bf16* __restrict__ up,
    bf16* __restrict__ act) {
  const size_t i = (size_t)blockIdx.x * 256 + threadIdx.x;
  bf16x8 g = ((const bf16x8*)gate)[i];
  bf16x8 u = ((const bf16x8*)up)[i];
  bf16x8 o;
#pragma unroll
  for (int j = 0; j < 8; j++) {
    const float gf = (float)g[j];
    const float sg = gf / (1.f + __expf(-gf));
    o[j] = (bf16)(sg * (float)u[j]);
  }
  ((bf16x8*)act)[i] = o;
}

// ---------------------------------------------------------------------------
extern "C" void kernel_launch(void* const* d_in, const int* in_sizes, int n_in,
                              void* d_out, int out_size, void* d_ws,
                              size_t ws_size, hipStream_t stream) {
  const float* x = (const float*)d_in[0];
  const float* cosT = (const float*)d_in[1];
  const float* sinT = (const float*)d_in[2];
  const float* anw = (const float*)d_in[3];
  const float* fnw = (const float*)d_in[4];
  const float* wq = (const float*)d_in[5];
  const float* wk = (const float*)d_in[6];
  const float* wv = (const float*)d_in[7];
  const float* wo = (const float*)d_in[8];
  const float* wg = (const float*)d_in[9];
  const float* wu = (const float*)d_in[10];
  const float* wd = (const float*)d_in[11];

  char* ws = (char*)d_ws;
  size_t off = 0;
  auto alloc = [&](size_t bytes) -> void* {
    void* p = ws + off;
    off += (bytes + 255) & ~(size_t)255;
    return p;
  };
  const size_t M = 2048;
  bf16* WQKVt = (bf16*)alloc(6144ULL * 4096 * 2);     // [6144][4096]
  bf16* WOt = (bf16*)alloc(4096ULL * 4096 * 2);       // [4096][4096]
  bf16* WGt = (bf16*)alloc((size_t)I_DIM * 4096 * 2); // [11008][4096]
  bf16* WUt = (bf16*)alloc((size_t)I_DIM * 4096 * 2);
  bf16* WDt = (bf16*)alloc(4096ULL * I_DIM * 2);      // [4096][11008]
  float* QKVf = (float*)alloc(M * 6144 * 4);          // also GATE/ACT (bf16)
  char* blkA = (char*)alloc(M * 14336 * 2);           // HIN,QB,KB,VT,ATTN; also UP
  float* H2 = (float*)alloc(M * 4096 * 4);
  bf16* MINb = (bf16*)alloc(M * 4096 * 2);

  bf16* HIN = (bf16*)blkA;
  bf16* QB = HIN + M * 4096;
  bf16* KB = QB + M * 4096;
  bf16* VT = KB + M * 1024;
  bf16* ATTN = VT + M * 1024;
  bf16* GATE = (bf16*)QKVf;   // qkv f32 dead by then
  bf16* UP = (bf16*)blkA;     // hin/qb/kb/vt/attn dead by then
  bf16* ACT = GATE;           // in-place swiglu

  // 1) weight transposes (fp32 -> bf16 [N][K])
  wtrans_kernel<<<dim3(128, 128), 256, 0, stream>>>(wq, WQKVt, 4096, 4096);
  wtrans_kernel<<<dim3(32, 128), 256, 0, stream>>>(wk, WQKVt + 4096ULL * 4096, 4096, 1024);
  wtrans_kernel<<<dim3(32, 128), 256, 0, stream>>>(wv, WQKVt + 5120ULL * 4096, 4096, 1024);
  wtrans_kernel<<<dim3(128, 128), 256, 0, stream>>>(wo, WOt, 4096, 4096);
  wtrans_kernel<<<dim3(344, 128), 256, 0, stream>>>(wg, WGt, 4096, I_DIM);
  wtrans_kernel<<<dim3(344, 128), 256, 0, stream>>>(wu, WUt, 4096, I_DIM);
  wtrans_kernel<<<dim3(128, 344), 256, 0, stream>>>(wd, WDt, I_DIM, 4096);

  // 2) attn rmsnorm -> bf16
  rmsnorm_kernel<<<2048, 256, 0, stream>>>(x, anw, HIN);
  // 3) fused QKV GEMM -> f32
  gemm_tn<1><<<dim3(48, 16), 256, 0, stream>>>(HIN, WQKVt, QKVf, nullptr, 2048, 6144, 4096);
  // 4) rope (q scaled by 1/sqrt(D))
  rope_kernel<<<2048, 256, 0, stream>>>(QKVf, cosT, sinT, QB, KB);
  // 5) v transpose -> [b][kv][d][s] bf16
  vtrans_kernel<<<dim3(32, 4, 16), 256, 0, stream>>>(QKVf, VT);
  // 6) flash attention
  attn_fwd<<<dim3(8, 32, 2), 256, 0, stream>>>(QB, KB, VT, ATTN);
  // 7) WO GEMM + residual(x) -> H2 f32
  gemm_tn<2><<<dim3(32, 16), 256, 0, stream>>>(ATTN, WOt, H2, x, 2048, 4096, 4096);
  // 8) ffn rmsnorm
  rmsnorm_kernel<<<2048, 256, 0, stream>>>(H2, fnw, MINb);
  // 9) gate / up GEMMs -> bf16
  gemm_tn<0><<<dim3(86, 16), 256, 0, stream>>>(MINb, WGt, GATE, nullptr, 2048, I_DIM, 4096);
  gemm_tn<0><<<dim3(86, 16), 256, 0, stream>>>(MINb, WUt, UP, nullptr, 2048, I_DIM, 4096);
  // 10) swiglu (in-place into GATE)
  swiglu_kernel<<<11008, 256, 0, stream>>>(GATE, UP, ACT);
  // 11) down GEMM + residual(H2) -> d_out f32
  gemm_tn<2><<<dim3(32, 16), 256, 0, stream>>>(ACT, WDt, d_out, H2, 2048, 4096, I_DIM);
}

// Round 2
// 1880.858 us; speedup vs baseline: 1.0324x; 1.0324x over previous
//
#include <hip/hip_runtime.h>
#include <cstdint>
#include <cstddef>

// ---------------------------------------------------------------------------
// Llama decoder layer, MI355X. B=2 S=1024 H=4096 NQ=32 NKV=8 D=128 I=11008.
// R2: m-fastest GEMM grid swizzle (L3-resident working set), vectorized
// 64x64 weight transpose, gate+up fused into one interleaved GEMM.
// ---------------------------------------------------------------------------

typedef __bf16 bf16;
typedef __attribute__((ext_vector_type(8))) __bf16 bf16x8;
typedef __attribute__((ext_vector_type(4))) float f32x4;

#define GLDS16(gptr, lptr)                                                    \
  __builtin_amdgcn_global_load_lds(                                           \
      (const __attribute__((address_space(1))) void*)(gptr),                  \
      (__attribute__((address_space(3))) void*)(lptr), 16, 0, 0)

#define S_LEN 1024
#define H_DIM 4096
#define NQ_H 32
#define NKV_H 8
#define HD 128
#define I_DIM 11008

// ---------------------------------------------------------------------------
// Weight transpose + fp32->bf16, 64x64 tiles, vectorized.
// src [K][N] f32 -> dst[( (n>>7)*tile_stride + (n&127) + base )][K] bf16.
// tile_stride=128,base=0 -> plain transpose. 256/0 + 256/128 interleave
// gate/up at 128-column granularity for the fused GU GEMM.
// ---------------------------------------------------------------------------
__global__ __launch_bounds__(256) void wtrans64_kernel(
    const float* __restrict__ src, bf16* __restrict__ dst, int K, int N,
    int tile_stride, int base) {
  const int tid = threadIdx.x;
  const int n0 = blockIdx.x * 64, k0 = blockIdx.y * 64;
  __shared__ float t[64][65];
  const int r = tid >> 4, c4 = (tid & 15) * 4;
#pragma unroll
  for (int j = 0; j < 4; j++) {
    const float4 v =
        *(const float4*)&src[(size_t)(k0 + r + j * 16) * N + n0 + c4];
    t[r + j * 16][c4 + 0] = v.x;
    t[r + j * 16][c4 + 1] = v.y;
    t[r + j * 16][c4 + 2] = v.z;
    t[r + j * 16][c4 + 3] = v.w;
  }
  __syncthreads();
  const int n = tid >> 2, kq = (tid & 3) * 16;
  bf16x8 o0, o1;
#pragma unroll
  for (int i = 0; i < 8; i++) {
    o0[i] = (bf16)t[kq + i][n];
    o1[i] = (bf16)t[kq + 8 + i][n];
  }
  const int ng = n0 + n;
  const size_t orow = (size_t)(ng >> 7) * tile_stride + (ng & 127) + base;
  *(bf16x8*)&dst[orow * K + k0 + kq] = o0;
  *(bf16x8*)&dst[orow * K + k0 + kq + 8] = o1;
}

// ---------------------------------------------------------------------------
// RMSNorm: x f32 [rows][4096] -> out bf16, one block per row
// ---------------------------------------------------------------------------
__global__ __launch_bounds__(256) void rmsnorm_kernel(
    const float* __restrict__ x, const float* __restrict__ w,
    bf16* __restrict__ out) {
  const int row = blockIdx.x;
  const float4* xr = (const float4*)(x + (size_t)row * H_DIM);
  float4 v[4];
  float s = 0.f;
#pragma unroll
  for (int i = 0; i < 4; i++) {
    v[i] = xr[threadIdx.x + i * 256];
    s += v[i].x * v[i].x + v[i].y * v[i].y + v[i].z * v[i].z + v[i].w * v[i].w;
  }
#pragma unroll
  for (int m = 1; m < 64; m <<= 1) s += __shfl_xor(s, m);
  __shared__ float red[4];
  if ((threadIdx.x & 63) == 0) red[threadIdx.x >> 6] = s;
  __syncthreads();
  s = red[0] + red[1] + red[2] + red[3];
  const float r = rsqrtf(s * (1.f / H_DIM) + 1e-5f);
  bf16* o = out + (size_t)row * H_DIM;
  const float4* wr = (const float4*)w;
#pragma unroll
  for (int i = 0; i < 4; i++) {
    float4 wv = wr[threadIdx.x + i * 256];
    int idx = (threadIdx.x + i * 256) * 4;
    o[idx + 0] = (bf16)(v[i].x * r * wv.x);
    o[idx + 1] = (bf16)(v[i].y * r * wv.y);
    o[idx + 2] = (bf16)(v[i].z * r * wv.z);
    o[idx + 3] = (bf16)(v[i].w * r * wv.w);
  }
}

// ---------------------------------------------------------------------------
// GEMM TN: C[M][N] = A[M][K](bf16) * Bt[N][K](bf16)^T.  M == 2048 (16 tiles).
// 1D grid, m-fastest: mt = id & 15, nt = id >> 4 -> 256 co-resident blocks
// span all m x 16 n-tiles; A(16MB)+B-slice stay L3-resident, B fetched once.
// MODE 0: bf16 out. MODE 1: f32 out. MODE 2: f32 out + resid add.
// ---------------------------------------------------------------------------
template <int MODE>
__global__ __launch_bounds__(256) void gemm_tn(
    const bf16* __restrict__ A, const bf16* __restrict__ Bt,
    void* __restrict__ Cout, const float* __restrict__ resid,
    int N, int K) {
  __shared__ __align__(16) bf16 As[128 * 32];
  __shared__ __align__(16) bf16 Bs[128 * 32];
  const int tid = threadIdx.x;
  const int wave = tid >> 6, lane = tid & 63;
  const int lr = lane & 15, quad = lane >> 4;
  const int m0 = (blockIdx.x & 15) * 128, n0 = (blockIdx.x >> 4) * 128;
  const int wm = (wave & 1) * 64, wn = (wave >> 1) * 64;

  const int c0 = wave * 2;
  const int ar0 = (c0 * 64 + lane) >> 2;
  const int ar1 = (c0 * 64 + 64 + lane) >> 2;
  const int acol = (lane & 3) * 8;
  const bf16* Ag0 = A + (size_t)(m0 + ar0) * K + acol;
  const bf16* Ag1 = A + (size_t)(m0 + ar1) * K + acol;
  const bf16* Bg0 = Bt + (size_t)(n0 + ar0) * K + acol;
  const bf16* Bg1 = Bt + (size_t)(n0 + ar1) * K + acol;
  bf16* As0 = As + c0 * 512;
  bf16* Bs0 = Bs + c0 * 512;

  f32x4 acc[4][4] = {};

  for (int k0 = 0; k0 < K; k0 += 32) {
    __syncthreads();
    GLDS16(Ag0 + k0, As0);
    GLDS16(Ag1 + k0, As0 + 512);
    GLDS16(Bg0 + k0, Bs0);
    GLDS16(Bg1 + k0, Bs0 + 512);
    __syncthreads();
    bf16x8 af[4], bfr[4];
#pragma unroll
    for (int i = 0; i < 4; i++)
      af[i] = *(const bf16x8*)&As[(wm + i * 16 + lr) * 32 + quad * 8];
#pragma unroll
    for (int j = 0; j < 4; j++)
      bfr[j] = *(const bf16x8*)&Bs[(wn + j * 16 + lr) * 32 + quad * 8];
#pragma unroll
    for (int i = 0; i < 4; i++)
#pragma unroll
      for (int j = 0; j < 4; j++)
        acc[i][j] = __builtin_amdgcn_mfma_f32_16x16x32_bf16(af[i], bfr[j],
                                                            acc[i][j], 0, 0, 0);
  }

#pragma unroll
  for (int i = 0; i < 4; i++)
#pragma unroll
    for (int j = 0; j < 4; j++)
#pragma unroll
      for (int r = 0; r < 4; r++) {
        const size_t row = m0 + wm + i * 16 + quad * 4 + r;
        const size_t col = n0 + wn + j * 16 + lr;
        const float v = acc[i][j][r];
        if (MODE == 0)
          ((bf16*)Cout)[row * N + col] = (bf16)v;
        else if (MODE == 1)
          ((float*)Cout)[row * N + col] = v;
        else
          ((float*)Cout)[row * N + col] = v + resid[row * N + col];
      }
}

// ---------------------------------------------------------------------------
// RoPE: qkv bf16 [2048][6144] -> qb bf16 [2048][4096] (scaled by 1/sqrt(D)),
//       kb bf16 [2048][1024]
// ---------------------------------------------------------------------------
__global__ __launch_bounds__(256) void rope_kernel(
    const bf16* __restrict__ qkv, const float* __restrict__ cosT,
    const float* __restrict__ sinT, bf16* __restrict__ qb,
    bf16* __restrict__ kb) {
  const int row = blockIdx.x;
  const int s = row & (S_LEN - 1);
  const bf16* base = qkv + (size_t)row * 6144;
  const float scale = 0.08838834764831845f;  // 1/sqrt(128)
  for (int p = threadIdx.x; p < 2560; p += 256) {
    const int hd = p >> 6;
    const int d = p & 63;
    const float c = cosT[s * HD + d], sn = sinT[s * HD + d];
    if (hd < NQ_H) {
      const bf16* qp = base + hd * HD;
      const float x1 = (float)qp[d], x2 = (float)qp[d + 64];
      bf16* o = qb + (size_t)row * H_DIM + hd * HD;
      o[d] = (bf16)((x1 * c - x2 * sn) * scale);
      o[d + 64] = (bf16)((x2 * c + x1 * sn) * scale);
    } else {
      const int kh = hd - NQ_H;
      const bf16* kp = base + H_DIM + kh * HD;
      const float x1 = (float)kp[d], x2 = (float)kp[d + 64];
      bf16* o = kb + (size_t)row * (NKV_H * HD) + kh * HD;
      o[d] = (bf16)(x1 * c - x2 * sn);
      o[d + 64] = (bf16)(x2 * c + x1 * sn);
    }
  }
}

// ---------------------------------------------------------------------------
// V transpose: qkv bf16 (v part at col 5120) -> vt bf16 [B][KV][128][S]
// ---------------------------------------------------------------------------
__global__ __launch_bounds__(256) void vtrans_kernel(
    const bf16* __restrict__ qkv, bf16* __restrict__ vt) {
  const int tx = threadIdx.x & 31, ty = threadIdx.x >> 5;
  const int s0 = blockIdx.x * 32, d0 = blockIdx.y * 32;
  const int b = blockIdx.z >> 3, kv = blockIdx.z & 7;
  __shared__ float t[32][33];
#pragma unroll
  for (int j = 0; j < 4; j++) {
    const int s = s0 + ty + j * 8;
    t[ty + j * 8][tx] =
        (float)qkv[(size_t)(b * S_LEN + s) * 6144 + 5120 + kv * HD + d0 + tx];
  }
  __syncthreads();
#pragma unroll
  for (int j = 0; j < 4; j++) {
    const int d = d0 + ty + j * 8;
    vt[((size_t)(b * NKV_H + kv) * HD + d) * S_LEN + s0 + tx] =
        (bf16)t[tx][ty + j * 8];
  }
}

// ---------------------------------------------------------------------------
// Flash attention. Grid (S/128, NQ, B), 256 threads (4 waves, 32 q-rows each).
// ---------------------------------------------------------------------------
__global__ __launch_bounds__(256) void attn_fwd(
    const bf16* __restrict__ Qb, const bf16* __restrict__ Kb,
    const bf16* __restrict__ Vtb, bf16* __restrict__ Ob) {
  __shared__ __align__(16) bf16 Ks[16 * 512];  // [4 ks][64 key][32 d]
  __shared__ __align__(16) bf16 Vs[16 * 512];  // [2 ks][128 d][32 key]
  __shared__ __align__(16) bf16 Ps[16 * 512];  // [2 ks][128 q][32 key]
  const int tid = threadIdx.x;
  const int wave = tid >> 6, lane = tid & 63;
  const int lr = lane & 15, quad = lane >> 4;
  const int qt = blockIdx.x, h = blockIdx.y, b = blockIdx.z;
  const int kv = h >> 2;
  const int qrow0 = qt * 128 + wave * 32;

  bf16x8 qf[2][4];
#pragma unroll
  for (int mi = 0; mi < 2; mi++)
#pragma unroll
    for (int ks = 0; ks < 4; ks++)
      qf[mi][ks] = *(const bf16x8*)&Qb[(size_t)(b * S_LEN + qrow0 + mi * 16 + lr) *
                                           H_DIM +
                                       h * HD + ks * 32 + quad * 8];

  f32x4 oacc[2][8] = {};
  float m_i[2][4], l_i[2][4];
#pragma unroll
  for (int mi = 0; mi < 2; mi++)
#pragma unroll
    for (int r = 0; r < 4; r++) {
      m_i[mi][r] = -__builtin_inff();
      l_i[mi][r] = 0.f;
    }

  const int nk = 2 * (qt + 1);
  const int maxrow = qrow0 + 31;
  const int srow = lane >> 2;
  const int scol = (lane & 3) * 8;

  for (int kt = 0; kt < nk; kt++) {
    const int k0 = kt * 64;
    __syncthreads();
#pragma unroll
    for (int i = 0; i < 4; i++) {
      const int c = wave * 4 + i;
      {
        const int ks = c >> 2, sc = c & 3;
        const int key = sc * 16 + srow;
        GLDS16(Kb + (size_t)(b * S_LEN + k0 + key) * (NKV_H * HD) + kv * HD +
                   ks * 32 + scol,
               Ks + c * 512);
      }
      {
        const int ks2 = c >> 3, sc2 = c & 7;
        const int d = sc2 * 16 + srow;
        GLDS16(Vtb + ((size_t)(b * NKV_H + kv) * HD + d) * S_LEN + k0 +
                   ks2 * 32 + scol,
               Vs + c * 512);
      }
    }
    __syncthreads();
    const bool active = (k0 <= maxrow);
    float alpha[2][4];
    if (active) {
      f32x4 sacc[2][4];
#pragma unroll
      for (int mi = 0; mi < 2; mi++)
#pragma unroll
        for (int nj = 0; nj < 4; nj++) sacc[mi][nj] = (f32x4){0.f, 0.f, 0.f, 0.f};
#pragma unroll
      for (int ks = 0; ks < 4; ks++) {
        bf16x8 kf[4];
#pragma unroll
        for (int nj = 0; nj < 4; nj++)
          kf[nj] = *(const bf16x8*)&Ks[ks * 2048 + (nj * 16 + lr) * 32 + quad * 8];
#pragma unroll
        for (int mi = 0; mi < 2; mi++)
#pragma unroll
          for (int nj = 0; nj < 4; nj++)
            sacc[mi][nj] = __builtin_amdgcn_mfma_f32_16x16x32_bf16(
                qf[mi][ks], kf[nj], sacc[mi][nj], 0, 0, 0);
      }
#pragma unroll
      for (int mi = 0; mi < 2; mi++) {
#pragma unroll
        for (int r = 0; r < 4; r++) {
          const int row = qrow0 + mi * 16 + quad * 4 + r;
          float best = -__builtin_inff();
#pragma unroll
          for (int nj = 0; nj < 4; nj++) {
            const int col = k0 + nj * 16 + lr;
            if (col > row) sacc[mi][nj][r] = -__builtin_inff();
            best = fmaxf(best, sacc[mi][nj][r]);
          }
#pragma unroll
          for (int m = 1; m < 16; m <<= 1)
            best = fmaxf(best, __shfl_xor(best, m));
          const float mnew = fmaxf(m_i[mi][r], best);
          alpha[mi][r] = __expf(m_i[mi][r] - mnew);
          m_i[mi][r] = mnew;
          float ssum = 0.f;
#pragma unroll
          for (int nj = 0; nj < 4; nj++) {
            const float p = __expf(sacc[mi][nj][r] - mnew);
            sacc[mi][nj][r] = p;
            ssum += p;
          }
#pragma unroll
          for (int m = 1; m < 16; m <<= 1) ssum += __shfl_xor(ssum, m);
          l_i[mi][r] = l_i[mi][r] * alpha[mi][r] + ssum;
        }
      }
#pragma unroll
      for (int mi = 0; mi < 2; mi++)
#pragma unroll
        for (int dj = 0; dj < 8; dj++)
#pragma unroll
          for (int r = 0; r < 4; r++) oacc[mi][dj][r] *= alpha[mi][r];
#pragma unroll
      for (int mi = 0; mi < 2; mi++)
#pragma unroll
        for (int nj = 0; nj < 4; nj++) {
          const int ks2 = nj >> 1;
          const int k32 = (nj & 1) * 16 + lr;
#pragma unroll
          for (int r = 0; r < 4; r++) {
            const int rowl = wave * 32 + mi * 16 + quad * 4 + r;
            Ps[ks2 * 4096 + rowl * 32 + k32] = (bf16)sacc[mi][nj][r];
          }
        }
    }
    __syncthreads();
    if (active) {
#pragma unroll
      for (int ks2 = 0; ks2 < 2; ks2++) {
        bf16x8 pf[2], vf[8];
#pragma unroll
        for (int mi = 0; mi < 2; mi++)
          pf[mi] = *(const bf16x8*)&Ps[ks2 * 4096 +
                                       (wave * 32 + mi * 16 + lr) * 32 + quad * 8];
#pragma unroll
        for (int dj = 0; dj < 8; dj++)
          vf[dj] = *(const bf16x8*)&Vs[ks2 * 4096 + (dj * 16 + lr) * 32 + quad * 8];
#pragma unroll
        for (int mi = 0; mi < 2; mi++)
#pragma unroll
          for (int dj = 0; dj < 8; dj++)
            oacc[mi][dj] = __builtin_amdgcn_mfma_f32_16x16x32_bf16(
                pf[mi], vf[dj], oacc[mi][dj], 0, 0, 0);
      }
    }
  }
#pragma unroll
  for (int mi = 0; mi < 2; mi++)
#pragma unroll
    for (int r = 0; r < 4; r++) {
      const float rinv = 1.f / l_i[mi][r];
      const size_t row = (size_t)b * S_LEN + qrow0 + mi * 16 + quad * 4 + r;
#pragma unroll
      for (int dj = 0; dj < 8; dj++)
        Ob[row * H_DIM + h * HD + dj * 16 + lr] =
            (bf16)(oacc[mi][dj][r] * rinv);
    }
}

// ---------------------------------------------------------------------------
// SwiGLU over interleaved GU [2048][22016] (gate tile / up tile alternating
// every 128 cols) -> act [2048][11008] bf16
// ---------------------------------------------------------------------------
__global__ __launch_bounds__(256) void swiglu_kernel(
    const bf16* __restrict__ gu, bf16* __restrict__ act) {
  const int gid = blockIdx.x * 256 + threadIdx.x;
  const int row = gid / 1376;        // 11008/8 groups per row
  const int c8 = (gid % 1376) * 8;
  const size_t gbase = (size_t)row * 22016 + (size_t)(c8 >> 7) * 256 + (c8 & 127);
  bf16x8 g = *(const bf16x8*)&gu[gbase];
  bf16x8 u = *(const bf16x8*)&gu[gbase + 128];
  bf16x8 o;
#pragma unroll
  for (int j = 0; j < 8; j++) {
    const float gf = (float)g[j];
    const float sg = gf / (1.f + __expf(-gf));
    o[j] = (bf16)(sg * (float)u[j]);
  }
  *(bf16x8*)&act[(size_t)row * I_DIM + c8] = o;
}

// ---------------------------------------------------------------------------
extern "C" void kernel_launch(void* const* d_in, const int* in_sizes, int n_in,
                              void* d_out, int out_size, void* d_ws,
                              size_t ws_size, hipStream_t stream) {
  const float* x = (const float*)d_in[0];
  const float* cosT = (const float*)d_in[1];
  const float* sinT = (const float*)d_in[2];
  const float* anw = (const float*)d_in[3];
  const float* fnw = (const float*)d_in[4];
  const float* wq = (const float*)d_in[5];
  const float* wk = (const float*)d_in[6];
  const float* wv = (const float*)d_in[7];
  const float* wo = (const float*)d_in[8];
  const float* wg = (const float*)d_in[9];
  const float* wu = (const float*)d_in[10];
  const float* wd = (const float*)d_in[11];

  char* ws = (char*)d_ws;
  size_t off = 0;
  auto alloc = [&](size_t bytes) -> void* {
    void* p = ws + off;
    off += (bytes + 255) & ~(size_t)255;
    return p;
  };
  const size_t M = 2048;
  bf16* WGUt = (bf16*)alloc(22016ULL * 4096 * 2);  // interleaved gate/up [N][K]
  bf16* WDt = (bf16*)alloc(4096ULL * I_DIM * 2);   // [4096][11008]
  char* R1 = (char*)alloc(90177536);               // WQKVt+WOt, later GU
  char* bufY = (char*)alloc(83886080);             // HIN..ATTN, later ACT
  float* H2 = (float*)alloc(M * 4096 * 4);
  bf16* MINb = (bf16*)alloc(M * 4096 * 2);

  bf16* WQKVt = (bf16*)R1;                       // [6144][4096]
  bf16* WOt = (bf16*)(R1 + 50331648);            // [4096][4096]
  bf16* GU = (bf16*)R1;                          // [2048][22016]
  bf16* HIN = (bf16*)bufY;                       // [2048][4096]
  bf16* QKVb = HIN + M * 4096;                   // [2048][6144]
  bf16* QB = QKVb + M * 6144;                    // [2048][4096]
  bf16* KB = QB + M * 4096;                      // [2048][1024]
  bf16* VT = KB + M * 1024;                      // [2][8][128][1024]
  bf16* ATTN = VT + M * 1024;                    // [2048][4096]
  bf16* ACT = (bf16*)bufY;                       // [2048][11008]

  // 1) weight transposes (fp32 -> bf16 [N][K]); gate/up interleaved
  wtrans64_kernel<<<dim3(64, 64), 256, 0, stream>>>(wq, WQKVt, 4096, 4096, 128, 0);
  wtrans64_kernel<<<dim3(16, 64), 256, 0, stream>>>(wk, WQKVt + 4096ULL * 4096, 4096, 1024, 128, 0);
  wtrans64_kernel<<<dim3(16, 64), 256, 0, stream>>>(wv, WQKVt + 5120ULL * 4096, 4096, 1024, 128, 0);
  wtrans64_kernel<<<dim3(64, 64), 256, 0, stream>>>(wo, WOt, 4096, 4096, 128, 0);
  wtrans64_kernel<<<dim3(172, 64), 256, 0, stream>>>(wg, WGUt, 4096, I_DIM, 256, 0);
  wtrans64_kernel<<<dim3(172, 64), 256, 0, stream>>>(wu, WGUt, 4096, I_DIM, 256, 128);
  wtrans64_kernel<<<dim3(64, 172), 256, 0, stream>>>(wd, WDt, I_DIM, 4096, 128, 0);

  // 2) attn rmsnorm -> bf16
  rmsnorm_kernel<<<2048, 256, 0, stream>>>(x, anw, HIN);
  // 3) fused QKV GEMM -> bf16
  gemm_tn<0><<<48 * 16, 256, 0, stream>>>(HIN, WQKVt, QKVb, nullptr, 6144, 4096);
  // 4) rope (q scaled by 1/sqrt(D))
  rope_kernel<<<2048, 256, 0, stream>>>(QKVb, cosT, sinT, QB, KB);
  // 5) v transpose -> [b][kv][d][s] bf16
  vtrans_kernel<<<dim3(32, 4, 16), 256, 0, stream>>>(QKVb, VT);
  // 6) flash attention
  attn_fwd<<<dim3(8, 32, 2), 256, 0, stream>>>(QB, KB, VT, ATTN);
  // 7) WO GEMM + residual(x) -> H2 f32
  gemm_tn<2><<<32 * 16, 256, 0, stream>>>(ATTN, WOt, H2, x, 4096, 4096);
  // 8) ffn rmsnorm
  rmsnorm_kernel<<<2048, 256, 0, stream>>>(H2, fnw, MINb);
  // 9) fused gate+up GEMM (interleaved N=22016) -> bf16
  gemm_tn<0><<<172 * 16, 256, 0, stream>>>(MINb, WGUt, GU, nullptr, 22016, 4096);
  // 10) swiglu -> ACT
  swiglu_kernel<<<11008, 256, 0, stream>>>(GU, ACT);
  // 11) down GEMM + residual(H2) -> d_out f32
  gemm_tn<2><<<32 * 16, 256, 0, stream>>>(ACT, WDt, d_out, H2, 4096, I_DIM);
}